// Round 16
// baseline (575.092 us; speedup 1.0000x reference)
//
#include <hip/hip_runtime.h>
#include <math.h>

// Problem constants
#define TT 16384   // tokens
#define HH 2048    // hidden
#define EE 64      // experts
#define KK 8       // top_k

#define TB 16          // tokens per block tile (one MFMA M-tile)
#define HC 64          // h per chunk (2 MFMA k-steps)
#define NCH (HH / HC)  // 32 chunks
#define KSPLIT 2
#define CPS (NCH / KSPLIT)  // 16 chunks per K-slice
#define TOPC 10
#define MARGIN_REL 8e-5f    // relative score margin (R14-validated)

// Output layout (flat float32):
// probs [TT][KK] | indices [TT][KK] | map [TT][EE] | aux scalar
#define IDX_OFF ((size_t)TT * KK)
#define MAP_OFF ((size_t)2 * TT * KK)
#define AUX_OFF ((size_t)2 * TT * KK + (size_t)TT * EE)

// d_ws: W bf16 hi/lo planes (fragment-native, R10-validated) | pbuf | counters
#define WSPLANE 131072
#define PBUF_OFF (2 * WSPLANE)            // shorts; byte 512 KB
#define NTILE (TT / TB)                   // 1024
#define PBUF_FLOATS ((size_t)NTILE * KSPLIT * 1024)   // 8 MB

typedef short bf16x8 __attribute__((ext_vector_type(8)));
typedef float f32x4  __attribute__((ext_vector_type(4)));

__device__ __forceinline__ unsigned short f2bf(float x) {   // RNE fp32->bf16
    unsigned int u = __float_as_uint(x);
    u += 0x7FFFu + ((u >> 16) & 1u);
    return (unsigned short)(u >> 16);
}
__device__ __forceinline__ float bf2f(unsigned short b) {
    return __uint_as_float(((unsigned int)b) << 16);
}
__device__ __forceinline__ void cvt4(const float4 v, ushort4* hi, ushort4* lo) {
    unsigned short h0 = f2bf(v.x), h1 = f2bf(v.y),
                   h2 = f2bf(v.z), h3 = f2bf(v.w);
    *hi = make_ushort4(h0, h1, h2, h3);
    *lo = make_ushort4(f2bf(v.x - bf2f(h0)), f2bf(v.y - bf2f(h1)),
                       f2bf(v.z - bf2f(h2)), f2bf(v.w - bf2f(h3)));
}

// ---- prep: gate_w fp32 -> bf16 hi/lo planes in fragment-native layout ----
__global__ __launch_bounds__(256)
void prep_kernel(const float* __restrict__ gw, unsigned short* __restrict__ ws)
{
    const int gid = blockIdx.x * 256 + threadIdx.x;
    const int e  = gid >> 9;
    const int k  = (gid & 511) * 4;
    float4 v = *(const float4*)(gw + (size_t)e * HH + k);
    ushort4 hi, lo;
    cvt4(v, &hi, &lo);
    const int off = (k >> 5) * 2048 + ((k >> 3) & 3) * 512 + e * 8 + (k & 7);
    *(ushort4*)(ws + off)           = hi;
    *(ushort4*)(ws + WSPLANE + off) = lo;
}

// ---- R14/R15-validated chunk body ----
#define CHUNKA(C, HV)                                                          \
  do {                                                                         \
    const unsigned short* bp_ = bBase + (size_t)(2 * (C)) * 2048;              \
    bf16x8 Bh0 = *(const bf16x8*)(bp_);                                        \
    bf16x8 Bl0 = *(const bf16x8*)(bp_ + WSPLANE);                              \
    bf16x8 Bh1 = *(const bf16x8*)(bp_ + 2048);                                 \
    bf16x8 Bl1 = *(const bf16x8*)(bp_ + 2048 + WSPLANE);                       \
    unsigned char* buf_ = smem + ((C) & 1) * 4096;                             \
    ushort4 hi_, lo_;                                                          \
    cvt4(HV, &hi_, &lo_);                                                      \
    *(ushort4*)(buf_ + hOff)        = hi_;                                     \
    *(ushort4*)(buf_ + 2048 + hOff) = lo_;                                     \
    __syncthreads();                                                           \
    if ((C) + 2 < climit) HV = *(const float4*)(hgp + ((C) + 2) * HC);         \
    bf16x8 Ah0 = *(const bf16x8*)(buf_ + aOff0);                               \
    bf16x8 Al0 = *(const bf16x8*)(buf_ + 2048 + aOff0);                        \
    bf16x8 Ah1 = *(const bf16x8*)(buf_ + aOff1);                               \
    bf16x8 Al1 = *(const bf16x8*)(buf_ + 2048 + aOff1);                        \
    acc = __builtin_amdgcn_mfma_f32_16x16x32_bf16(Ah0, Bl0, acc, 0, 0, 0);     \
    acc = __builtin_amdgcn_mfma_f32_16x16x32_bf16(Al0, Bh0, acc, 0, 0, 0);     \
    acc = __builtin_amdgcn_mfma_f32_16x16x32_bf16(Ah0, Bh0, acc, 0, 0, 0);     \
    acc = __builtin_amdgcn_mfma_f32_16x16x32_bf16(Ah1, Bl1, acc, 0, 0, 0);     \
    acc = __builtin_amdgcn_mfma_f32_16x16x32_bf16(Al1, Bh1, acc, 0, 0, 0);     \
    acc = __builtin_amdgcn_mfma_f32_16x16x32_bf16(Ah1, Bh1, acc, 0, 0, 0);     \
  } while (0)

// ---- fused: split-K GEMM + last-arriver epilogue (one kernel) ----
__global__ __launch_bounds__(256, 8)
void fused_kernel(const float* __restrict__ hidden,
                  const float* __restrict__ gate_w,
                  const float* __restrict__ bias,
                  const unsigned short* __restrict__ wsbuf,
                  float* __restrict__ pbuf,
                  unsigned int* __restrict__ cnt,
                  float* __restrict__ out)
{
    __shared__ __align__(16) unsigned char smem[8192];
    __shared__ int winner;

    const int tid  = threadIdx.x;
    const int bid  = blockIdx.x;
    const int tile = bid >> 1;
    const int ks   = bid & 1;
    const int tok0 = tile * TB;
    const int c0   = ks * CPS;
    const int climit = c0 + CPS;

    // staging coords (validated)
    const int hr  = tid >> 4;
    const int hc4 = tid & 15;
    const float* hgp = hidden + (size_t)(tok0 + hr) * HH + hc4 * 4;
    const int hOff = hr * 128 + ((hc4 * 8) ^ ((hr & 7) << 4));

    // fragment coords (validated)
    const int lane = tid & 63;
    const int e0   = (tid >> 6) * 16;
    const int rx   = lane & 15;
    const int kq   = lane >> 4;
    const int aOff0 = rx * 128 + ((kq * 16) ^ ((rx & 7) << 4));
    const int aOff1 = aOff0 ^ 64;
    const unsigned short* bBase = wsbuf + kq * 512 + (e0 + rx) * 8;

    f32x4 acc = {0.f, 0.f, 0.f, 0.f};

    float4 hvA = *(const float4*)(hgp + c0 * HC);
    float4 hvB = *(const float4*)(hgp + (c0 + 1) * HC);

    for (int c = c0; c < climit; c += 2) {
        CHUNKA(c, hvA);
        CHUNKA(c + 1, hvB);
    }

    // ---- publish partial (agent-scope stores), then arrive ----
    {
        float* pp = pbuf + (size_t)bid * 1024 + tid * 4;
        __hip_atomic_store(pp + 0, acc[0], __ATOMIC_RELAXED, __HIP_MEMORY_SCOPE_AGENT);
        __hip_atomic_store(pp + 1, acc[1], __ATOMIC_RELAXED, __HIP_MEMORY_SCOPE_AGENT);
        __hip_atomic_store(pp + 2, acc[2], __ATOMIC_RELAXED, __HIP_MEMORY_SCOPE_AGENT);
        __hip_atomic_store(pp + 3, acc[3], __ATOMIC_RELAXED, __HIP_MEMORY_SCOPE_AGENT);
    }
    __threadfence();      // release
    __syncthreads();
    if (tid == 0) {
        unsigned old = atomicAdd(&cnt[tile], 1u);   // device scope
        winner = (old == 1);
    }
    __syncthreads();
    if (!winner) return;
    __threadfence();      // acquire

    // ---- sum sibling partial (agent-scope loads; commutative -> determin.) ----
    {
        const float* op = pbuf + (size_t)(tile * 2 + (ks ^ 1)) * 1024 + tid * 4;
        acc[0] += __hip_atomic_load(op + 0, __ATOMIC_RELAXED, __HIP_MEMORY_SCOPE_AGENT);
        acc[1] += __hip_atomic_load(op + 1, __ATOMIC_RELAXED, __HIP_MEMORY_SCOPE_AGENT);
        acc[2] += __hip_atomic_load(op + 2, __ATOMIC_RELAXED, __HIP_MEMORY_SCOPE_AGENT);
        acc[3] += __hip_atomic_load(op + 3, __ATOMIC_RELAXED, __HIP_MEMORY_SCOPE_AGENT);
    }

    // ---- logits to LDS (overlays staging; all block compute done) ----
    float* lg = (float*)smem;   // [16][68]
    __syncthreads();
    #pragma unroll
    for (int r = 0; r < 4; ++r)
        lg[(4 * kq + r) * 68 + e0 + rx] = acc[r];
    __syncthreads();

    // ---- epilogue: 16 lanes per token (R14-validated verbatim) ----
    const int t   = tid >> 4;
    const int q   = tid & 15;
    const int tok = tok0 + t;

    float lv[4];
    #pragma unroll
    for (int i = 0; i < 4; ++i) lv[i] = lg[t * 68 + q + 16 * i];

    float mx = lv[0];
    #pragma unroll
    for (int i = 1; i < 4; ++i) mx = fmaxf(mx, lv[i]);
    #pragma unroll
    for (int sh = 1; sh < 16; sh <<= 1) mx = fmaxf(mx, __shfl_xor(mx, sh, 64));

    float ex[4], psum = 0.0f;
    #pragma unroll
    for (int i = 0; i < 4; ++i) { ex[i] = expf(lv[i] - mx); psum += ex[i]; }
    #pragma unroll
    for (int sh = 1; sh < 16; sh <<= 1) psum += __shfl_xor(psum, sh, 64);
    const float inv = 1.0f / psum;

    float pr[4], selv[4];
    #pragma unroll
    for (int i = 0; i < 4; ++i) {
        pr[i]   = ex[i] * inv;
        selv[i] = pr[i] + bias[q + 16 * i];
    }

    float ws_[TOPC], wp[TOPC];
    int   wi[TOPC];
    #pragma unroll
    for (int k = 0; k < TOPC; ++k) {
        float bs = selv[0], bp = pr[0];
        int bi = q;
        #pragma unroll
        for (int i = 1; i < 4; ++i)
            if (selv[i] > bs) { bs = selv[i]; bp = pr[i]; bi = q + 16 * i; }
        #pragma unroll
        for (int sh = 1; sh < 16; sh <<= 1) {
            float os = __shfl_xor(bs, sh, 64);
            float op = __shfl_xor(bp, sh, 64);
            int   ob = __shfl_xor(bi, sh, 64);
            if (os > bs || (os == bs && ob < bi)) { bs = os; bp = op; bi = ob; }
        }
        ws_[k] = bs; wp[k] = bp; wi[k] = bi;
        #pragma unroll
        for (int i = 0; i < 4; ++i)
            if (q + 16 * i == bi) selv[i] = -INFINITY;
    }

    bool flag = false;
    #pragma unroll
    for (int k = 0; k < 8; ++k)
        flag = flag || (ws_[k] - ws_[k + 1] <
                        (ws_[k] + ws_[k + 1]) * MARGIN_REL + 1e-12f);

    if (flag) {
        const float* hrow = hidden + (size_t)tok * HH;
        const float* wr_[TOPC];
        #pragma unroll
        for (int k = 0; k < TOPC; ++k) wr_[k] = gate_w + (size_t)wi[k] * HH;

        double l64[TOPC];
        #pragma unroll
        for (int k = 0; k < TOPC; ++k) l64[k] = 0.0;

        for (int m = 0; m < 32; ++m) {
            float4 h4 = *(const float4*)(hrow + m * 64 + 4 * q);
            double h0 = h4.x, h1 = h4.y, h2 = h4.z, h3 = h4.w;
            #pragma unroll
            for (int k = 0; k < TOPC; ++k) {
                float4 w4 = *(const float4*)(wr_[k] + m * 64 + 4 * q);
                l64[k] = fma(h0, (double)w4.x, l64[k]);
                l64[k] = fma(h1, (double)w4.y, l64[k]);
                l64[k] = fma(h2, (double)w4.z, l64[k]);
                l64[k] = fma(h3, (double)w4.w, l64[k]);
            }
        }
        #pragma unroll
        for (int k = 0; k < TOPC; ++k)
            #pragma unroll
            for (int sh = 1; sh < 16; sh <<= 1)
                l64[k] += __shfl_xor(l64[k], sh, 64);

        double s64[TOPC];
        #pragma unroll
        for (int k = 0; k < TOPC; ++k)
            s64[k] = exp(l64[k] - (double)mx) * (double)inv + (double)bias[wi[k]];

        #pragma unroll
        for (int a = 0; a < 8; ++a) {
            #pragma unroll
            for (int b = a + 1; b < TOPC; ++b) {
                bool sw = (s64[b] > s64[a]) ||
                          (s64[b] == s64[a] && wi[b] < wi[a]);
                if (sw) {
                    double td = s64[a]; s64[a] = s64[b]; s64[b] = td;
                    int    ti = wi[a];  wi[a]  = wi[b];  wi[b]  = ti;
                    float  tp = wp[a];  wp[a]  = wp[b];  wp[b]  = tp;
                }
            }
        }
    }

    int oi = wi[0];
    float opf = wp[0];
    #pragma unroll
    for (int k = 1; k < 8; ++k)
        if (q == k) { oi = wi[k]; opf = wp[k]; }

    float ps = 0.0f;
    #pragma unroll
    for (int k = 0; k < 8; ++k) ps += wp[k];
    const float rinv = 1.0f / (ps + 1e-9f);

    if (q < KK) {
        out[(size_t)tok * KK + q]           = opf * rinv;
        out[IDX_OFF + (size_t)tok * KK + q] = (float)oi;
    }

    unsigned long long mk = 0ull;
    #pragma unroll
    for (int k = 0; k < 8; ++k) mk |= (1ull << wi[k]);

    {
        float4 a;
        a.x = ((mk >> (4 * q + 0)) & 1ull) ? 1.0f : 0.0f;
        a.y = ((mk >> (4 * q + 1)) & 1ull) ? 1.0f : 0.0f;
        a.z = ((mk >> (4 * q + 2)) & 1ull) ? 1.0f : 0.0f;
        a.w = ((mk >> (4 * q + 3)) & 1ull) ? 1.0f : 0.0f;
        *(float4*)(out + MAP_OFF + (size_t)tok * EE + 4 * q) = a;
    }

    if (tile == 0 && tid == 0) out[AUX_OFF] = 0.0f;
}

extern "C" void kernel_launch(void* const* d_in, const int* in_sizes, int n_in,
                              void* d_out, int out_size, void* d_ws, size_t ws_size,
                              hipStream_t stream) {
    const float* hidden = (const float*)d_in[0];  // [16384, 2048] f32
    const float* gate_w = (const float*)d_in[1];  // [64, 2048] f32
    const float* bias   = (const float*)d_in[2];  // [64] f32
    float* out = (float*)d_out;
    unsigned short* ws = (unsigned short*)d_ws;   // 512 KB W + 8 MB pbuf + 4 KB cnt
    float* pbuf = (float*)(ws + PBUF_OFF);
    unsigned int* cnt = (unsigned int*)(pbuf + PBUF_FLOATS);

    hipMemsetAsync(cnt, 0, NTILE * sizeof(unsigned int), stream);
    prep_kernel<<<128, 256, 0, stream>>>(gate_w, ws);
    fused_kernel<<<NTILE * KSPLIT, 256, 0, stream>>>(hidden, gate_w, bias, ws,
                                                     pbuf, cnt, out);
}

// Round 17
// 67.554 us; speedup vs baseline: 8.5131x; 8.5131x over previous
//
#include <hip/hip_runtime.h>
#include <math.h>

// Problem constants
#define TT 16384
#define HH 2048
#define EE 64
#define KK 8

#define TB 16
#define HC 64
#define NCH (HH / HC)
#define KSPLIT 2
#define CPS (NCH / KSPLIT)
#define TOPC 10
#define MARGIN_REL 8e-5f

// Output layout (flat float32):
#define IDX_OFF ((size_t)TT * KK)
#define MAP_OFF ((size_t)2 * TT * KK)
#define AUX_OFF ((size_t)2 * TT * KK + (size_t)TT * EE)

// d_ws byte layout:
//   [0, 512K)        W bf16 hi/lo planes (fragment-native, R10-validated)
//   [512K, 512K+8M)  pbuf: [bid][tid][4] f32 partials
//   NFLAG_B          1 uint counter (+pad)
//   LIST_B           16384 uint token ids (compacted flagged list)
//   RECI_B           16384 x 10 int   candidate indices
//   RECF_B           16384 x 12 float candidate probs + mx + inv
#define WSPLANE 131072
#define PBUF_B   524288
#define NFLAG_B  8913184   // 524288 + 8388608 = 8912896, pad to 8913184 (32-align)
#define LIST_B   8913216
#define RECI_B   8978752
#define RECF_B   9634112
#define NTILE (TT / TB)

typedef short bf16x8 __attribute__((ext_vector_type(8)));
typedef float f32x4  __attribute__((ext_vector_type(4)));

__device__ __forceinline__ unsigned short f2bf(float x) {
    unsigned int u = __float_as_uint(x);
    u += 0x7FFFu + ((u >> 16) & 1u);
    return (unsigned short)(u >> 16);
}
__device__ __forceinline__ float bf2f(unsigned short b) {
    return __uint_as_float(((unsigned int)b) << 16);
}
__device__ __forceinline__ void cvt4(const float4 v, ushort4* hi, ushort4* lo) {
    unsigned short h0 = f2bf(v.x), h1 = f2bf(v.y),
                   h2 = f2bf(v.z), h3 = f2bf(v.w);
    *hi = make_ushort4(h0, h1, h2, h3);
    *lo = make_ushort4(f2bf(v.x - bf2f(h0)), f2bf(v.y - bf2f(h1)),
                       f2bf(v.z - bf2f(h2)), f2bf(v.w - bf2f(h3)));
}

__global__ __launch_bounds__(256)
void prep_kernel(const float* __restrict__ gw, unsigned short* __restrict__ ws)
{
    const int gid = blockIdx.x * 256 + threadIdx.x;
    const int e  = gid >> 9;
    const int k  = (gid & 511) * 4;
    float4 v = *(const float4*)(gw + (size_t)e * HH + k);
    ushort4 hi, lo;
    cvt4(v, &hi, &lo);
    const int off = (k >> 5) * 2048 + ((k >> 3) & 3) * 512 + e * 8 + (k & 7);
    *(ushort4*)(ws + off)           = hi;
    *(ushort4*)(ws + WSPLANE + off) = lo;
}

#define CHUNKA(C, HV)                                                          \
  do {                                                                         \
    const unsigned short* bp_ = bBase + (size_t)(2 * (C)) * 2048;              \
    bf16x8 Bh0 = *(const bf16x8*)(bp_);                                        \
    bf16x8 Bl0 = *(const bf16x8*)(bp_ + WSPLANE);                              \
    bf16x8 Bh1 = *(const bf16x8*)(bp_ + 2048);                                 \
    bf16x8 Bl1 = *(const bf16x8*)(bp_ + 2048 + WSPLANE);                       \
    unsigned char* buf_ = smem + ((C) & 1) * 4096;                             \
    ushort4 hi_, lo_;                                                          \
    cvt4(HV, &hi_, &lo_);                                                      \
    *(ushort4*)(buf_ + hOff)        = hi_;                                     \
    *(ushort4*)(buf_ + 2048 + hOff) = lo_;                                     \
    __syncthreads();                                                           \
    if ((C) + 2 < climit) HV = *(const float4*)(hgp + ((C) + 2) * HC);         \
    bf16x8 Ah0 = *(const bf16x8*)(buf_ + aOff0);                               \
    bf16x8 Al0 = *(const bf16x8*)(buf_ + 2048 + aOff0);                        \
    bf16x8 Ah1 = *(const bf16x8*)(buf_ + aOff1);                               \
    bf16x8 Al1 = *(const bf16x8*)(buf_ + 2048 + aOff1);                        \
    acc = __builtin_amdgcn_mfma_f32_16x16x32_bf16(Ah0, Bl0, acc, 0, 0, 0);     \
    acc = __builtin_amdgcn_mfma_f32_16x16x32_bf16(Al0, Bh0, acc, 0, 0, 0);     \
    acc = __builtin_amdgcn_mfma_f32_16x16x32_bf16(Ah0, Bh0, acc, 0, 0, 0);     \
    acc = __builtin_amdgcn_mfma_f32_16x16x32_bf16(Ah1, Bl1, acc, 0, 0, 0);     \
    acc = __builtin_amdgcn_mfma_f32_16x16x32_bf16(Al1, Bh1, acc, 0, 0, 0);     \
    acc = __builtin_amdgcn_mfma_f32_16x16x32_bf16(Ah1, Bh1, acc, 0, 0, 0);     \
  } while (0)

__global__ __launch_bounds__(256, 8)
void gemm_partial(const float* __restrict__ hidden,
                  const unsigned short* __restrict__ wsbuf,
                  float* __restrict__ pbuf)
{
    __shared__ __align__(16) unsigned char smem[8192];

    const int tid  = threadIdx.x;
    const int bid  = blockIdx.x;
    const int tile = bid >> 1;
    const int ks   = bid & 1;
    const int tok0 = tile * TB;
    const int c0   = ks * CPS;
    const int climit = c0 + CPS;

    const int hr  = tid >> 4;
    const int hc4 = tid & 15;
    const float* hgp = hidden + (size_t)(tok0 + hr) * HH + hc4 * 4;
    const int hOff = hr * 128 + ((hc4 * 8) ^ ((hr & 7) << 4));

    const int lane = tid & 63;
    const int e0   = (tid >> 6) * 16;
    const int rx   = lane & 15;
    const int kq   = lane >> 4;
    const int aOff0 = rx * 128 + ((kq * 16) ^ ((rx & 7) << 4));
    const int aOff1 = aOff0 ^ 64;
    const unsigned short* bBase = wsbuf + kq * 512 + (e0 + rx) * 8;

    f32x4 acc = {0.f, 0.f, 0.f, 0.f};

    float4 hvA = *(const float4*)(hgp + c0 * HC);
    float4 hvB = *(const float4*)(hgp + (c0 + 1) * HC);

    for (int c = c0; c < climit; c += 2) {
        CHUNKA(c, hvA);
        CHUNKA(c + 1, hvB);
    }

    *(f32x4*)(pbuf + (size_t)bid * 1024 + tid * 4) = acc;
}

// ---- reduce + fp32 epilogue; flagged tokens -> record + compacted append ----
__global__ __launch_bounds__(256, 4)
void reduce_epilogue(const float* __restrict__ pbuf,
                     const float* __restrict__ bias,
                     unsigned int* __restrict__ nflag,
                     unsigned int* __restrict__ list,
                     int* __restrict__ recI,
                     float* __restrict__ recF,
                     float* __restrict__ out)
{
    __shared__ __align__(16) float lg[16 * 68 + 8];

    const int tid  = threadIdx.x;
    const int tile = blockIdx.x;
    const int tok0 = tile * TB;

    f32x4 a0 = *(const f32x4*)(pbuf + (size_t)(tile * 2 + 0) * 1024 + tid * 4);
    f32x4 a1 = *(const f32x4*)(pbuf + (size_t)(tile * 2 + 1) * 1024 + tid * 4);
    f32x4 acc = a0 + a1;

    const int lane = tid & 63;
    const int e0   = (tid >> 6) * 16;
    const int rx   = lane & 15;
    const int kq   = lane >> 4;

    #pragma unroll
    for (int r = 0; r < 4; ++r)
        lg[(4 * kq + r) * 68 + e0 + rx] = acc[r];
    __syncthreads();

    const int t   = tid >> 4;
    const int q   = tid & 15;
    const int tok = tok0 + t;

    float lv[4];
    #pragma unroll
    for (int i = 0; i < 4; ++i) lv[i] = lg[t * 68 + q + 16 * i];

    float mx = lv[0];
    #pragma unroll
    for (int i = 1; i < 4; ++i) mx = fmaxf(mx, lv[i]);
    #pragma unroll
    for (int sh = 1; sh < 16; sh <<= 1) mx = fmaxf(mx, __shfl_xor(mx, sh, 64));

    float ex[4], psum = 0.0f;
    #pragma unroll
    for (int i = 0; i < 4; ++i) { ex[i] = expf(lv[i] - mx); psum += ex[i]; }
    #pragma unroll
    for (int sh = 1; sh < 16; sh <<= 1) psum += __shfl_xor(psum, sh, 64);
    const float inv = 1.0f / psum;

    float pr[4], selv[4];
    #pragma unroll
    for (int i = 0; i < 4; ++i) {
        pr[i]   = ex[i] * inv;
        selv[i] = pr[i] + bias[q + 16 * i];
    }

    float ws_[TOPC], wp[TOPC];
    int   wi[TOPC];
    #pragma unroll
    for (int k = 0; k < TOPC; ++k) {
        float bs = selv[0], bp = pr[0];
        int bi = q;
        #pragma unroll
        for (int i = 1; i < 4; ++i)
            if (selv[i] > bs) { bs = selv[i]; bp = pr[i]; bi = q + 16 * i; }
        #pragma unroll
        for (int sh = 1; sh < 16; sh <<= 1) {
            float os = __shfl_xor(bs, sh, 64);
            float op = __shfl_xor(bp, sh, 64);
            int   ob = __shfl_xor(bi, sh, 64);
            if (os > bs || (os == bs && ob < bi)) { bs = os; bp = op; bi = ob; }
        }
        ws_[k] = bs; wp[k] = bp; wi[k] = bi;
        #pragma unroll
        for (int i = 0; i < 4; ++i)
            if (q + 16 * i == bi) selv[i] = -INFINITY;
    }

    bool flag = false;
    #pragma unroll
    for (int k = 0; k < 8; ++k)
        flag = flag || (ws_[k] - ws_[k + 1] <
                        (ws_[k] + ws_[k + 1]) * MARGIN_REL + 1e-12f);

    // record candidates for flagged tokens (static-index extraction, rule #20)
    {
        int   mywi = wi[0];
        float mywp = wp[0];
        #pragma unroll
        for (int k = 1; k < TOPC; ++k)
            if (q == k) { mywi = wi[k]; mywp = wp[k]; }
        if (flag && q < TOPC) {
            recI[(size_t)tok * 10 + q] = mywi;
            recF[(size_t)tok * 12 + q] = mywp;
        }
        if (flag && q == 0) {
            recF[(size_t)tok * 12 + 10] = mx;
            recF[(size_t)tok * 12 + 11] = inv;
            unsigned int o = atomicAdd(nflag, 1u);
            list[o] = (unsigned int)tok;
        }
    }

    // provisional outputs (overwritten by fixup for flagged tokens)
    int oi = wi[0];
    float opf = wp[0];
    #pragma unroll
    for (int k = 1; k < 8; ++k)
        if (q == k) { oi = wi[k]; opf = wp[k]; }

    float ps = 0.0f;
    #pragma unroll
    for (int k = 0; k < 8; ++k) ps += wp[k];
    const float rinv = 1.0f / (ps + 1e-9f);

    if (q < KK) {
        out[(size_t)tok * KK + q]           = opf * rinv;
        out[IDX_OFF + (size_t)tok * KK + q] = (float)oi;
    }

    unsigned long long mk = 0ull;
    #pragma unroll
    for (int k = 0; k < 8; ++k) mk |= (1ull << wi[k]);

    {
        float4 a;
        a.x = ((mk >> (4 * q + 0)) & 1ull) ? 1.0f : 0.0f;
        a.y = ((mk >> (4 * q + 1)) & 1ull) ? 1.0f : 0.0f;
        a.z = ((mk >> (4 * q + 2)) & 1ull) ? 1.0f : 0.0f;
        a.w = ((mk >> (4 * q + 3)) & 1ull) ? 1.0f : 0.0f;
        *(float4*)(out + MAP_OFF + (size_t)tok * EE + 4 * q) = a;
    }

    if (tile == 0 && tid == 0) out[AUX_OFF] = 0.0f;
}

// ---- fixup: one 256-thread block per flagged token (grid-stride list) ----
__global__ __launch_bounds__(256, 4)
void fixup_kernel(const float* __restrict__ hidden,
                  const float* __restrict__ gate_w,
                  const float* __restrict__ bias,
                  const unsigned int* __restrict__ nflag,
                  const unsigned int* __restrict__ list,
                  const int* __restrict__ recI,
                  const float* __restrict__ recF,
                  float* __restrict__ out)
{
    __shared__ double redL[4][12];

    const int tid  = threadIdx.x;
    const int wv   = tid >> 6;
    const int lane = tid & 63;
    const unsigned int nf = *nflag;

    for (unsigned int i = blockIdx.x; i < nf; i += gridDim.x) {
        const int tok = (int)list[i];

        int   wk[TOPC];
        #pragma unroll
        for (int k = 0; k < TOPC; ++k) wk[k] = recI[(size_t)tok * 10 + k];
        const float mx  = recF[(size_t)tok * 12 + 10];
        const float inv = recF[(size_t)tok * 12 + 11];

        // fp64 dots: thread covers h in [tid*8, tid*8+8)
        const float* hp = hidden + (size_t)tok * HH + tid * 8;
        float4 ha = *(const float4*)(hp);
        float4 hb = *(const float4*)(hp + 4);
        double h0 = ha.x, h1 = ha.y, h2 = ha.z, h3 = ha.w;
        double h4 = hb.x, h5 = hb.y, h6 = hb.z, h7 = hb.w;

        double l64[TOPC];
        #pragma unroll
        for (int k = 0; k < TOPC; ++k) {
            const float* wpt = gate_w + (size_t)wk[k] * HH + tid * 8;
            float4 wa = *(const float4*)(wpt);
            float4 wb = *(const float4*)(wpt + 4);
            double s = 0.0;
            s = fma(h0, (double)wa.x, s); s = fma(h1, (double)wa.y, s);
            s = fma(h2, (double)wa.z, s); s = fma(h3, (double)wa.w, s);
            s = fma(h4, (double)wb.x, s); s = fma(h5, (double)wb.y, s);
            s = fma(h6, (double)wb.z, s); s = fma(h7, (double)wb.w, s);
            l64[k] = s;
        }
        #pragma unroll
        for (int k = 0; k < TOPC; ++k)
            #pragma unroll
            for (int sh = 1; sh < 64; sh <<= 1)
                l64[k] += __shfl_xor(l64[k], sh, 64);
        if (lane == 0)
            #pragma unroll
            for (int k = 0; k < TOPC; ++k) redL[wv][k] = l64[k];
        __syncthreads();

        if (tid == 0) {
            double s64[TOPC];
            int    wi2[TOPC];
            float  wp2[TOPC];
            #pragma unroll
            for (int k = 0; k < TOPC; ++k) {
                double lk = redL[0][k] + redL[1][k] + redL[2][k] + redL[3][k];
                s64[k] = exp(lk - (double)mx) * (double)inv +
                         (double)bias[wk[k]];
                wi2[k] = wk[k];
                wp2[k] = recF[(size_t)tok * 12 + k];
            }
            // validated comparator: score desc, idx asc
            #pragma unroll
            for (int a = 0; a < 8; ++a) {
                #pragma unroll
                for (int b = a + 1; b < TOPC; ++b) {
                    bool sw = (s64[b] > s64[a]) ||
                              (s64[b] == s64[a] && wi2[b] < wi2[a]);
                    if (sw) {
                        double td = s64[a]; s64[a] = s64[b]; s64[b] = td;
                        int    ti = wi2[a]; wi2[a] = wi2[b]; wi2[b] = ti;
                        float  tp = wp2[a]; wp2[a] = wp2[b]; wp2[b] = tp;
                    }
                }
            }
            float ps = 0.0f;
            #pragma unroll
            for (int k = 0; k < 8; ++k) ps += wp2[k];
            const float rinv = 1.0f / (ps + 1e-9f);
            unsigned long long mk = 0ull;
            #pragma unroll
            for (int k = 0; k < 8; ++k) {
                out[(size_t)tok * KK + k]           = wp2[k] * rinv;
                out[IDX_OFF + (size_t)tok * KK + k] = (float)wi2[k];
                mk |= (1ull << wi2[k]);
            }
            for (int e = 0; e < EE; ++e)
                out[MAP_OFF + (size_t)tok * EE + e] =
                    ((mk >> e) & 1ull) ? 1.0f : 0.0f;
        }
        __syncthreads();
    }
}

extern "C" void kernel_launch(void* const* d_in, const int* in_sizes, int n_in,
                              void* d_out, int out_size, void* d_ws, size_t ws_size,
                              hipStream_t stream) {
    const float* hidden = (const float*)d_in[0];
    const float* gate_w = (const float*)d_in[1];
    const float* bias   = (const float*)d_in[2];
    float* out = (float*)d_out;

    char* wsb = (char*)d_ws;
    unsigned short* wplanes = (unsigned short*)wsb;
    float*        pbuf  = (float*)(wsb + PBUF_B);
    unsigned int* nflag = (unsigned int*)(wsb + NFLAG_B);
    unsigned int* list  = (unsigned int*)(wsb + LIST_B);
    int*          recI  = (int*)(wsb + RECI_B);
    float*        recF  = (float*)(wsb + RECF_B);

    hipMemsetAsync(nflag, 0, 32, stream);
    prep_kernel<<<128, 256, 0, stream>>>(gate_w, wplanes);
    gemm_partial<<<NTILE * KSPLIT, 256, 0, stream>>>(hidden, wplanes, pbuf);
    reduce_epilogue<<<NTILE, 256, 0, stream>>>(pbuf, bias, nflag, list,
                                               recI, recF, out);
    fixup_kernel<<<256, 256, 0, stream>>>(hidden, gate_w, bias, nflag, list,
                                          recI, recF, out);
}

// Round 18
// 65.231 us; speedup vs baseline: 8.8162x; 1.0356x over previous
//
#include <hip/hip_runtime.h>
#include <math.h>

// Problem constants
#define TT 16384
#define HH 2048
#define EE 64
#define KK 8

#define TB 16
#define HC 64
#define NCH (HH / HC)
#define KSPLIT 4
#define CPS (NCH / KSPLIT)   // 8 chunks per K-slice
#define TOPC 10
#define MARGIN_REL 8e-5f

// Output layout (flat float32):
#define IDX_OFF ((size_t)TT * KK)
#define MAP_OFF ((size_t)2 * TT * KK)
#define AUX_OFF ((size_t)2 * TT * KK + (size_t)TT * EE)

// d_ws byte layout:
//   [0, 512K)         W bf16 hi/lo planes (fragment-native, R10-validated)
//   [512K, 512K+16M)  pbuf: [bid][tid][4] f32 partials (4096 blocks x 4 KB)
//   NFLAG_B           1 uint counter (+pad)
//   LIST_B            16384 uint token ids (compacted flagged list)
//   RECI_B            16384 x 10 int   candidate indices
//   RECF_B            16384 x 12 float candidate probs + mx + inv
#define WSPLANE 131072
#define PBUF_B   524288
#define NFLAG_B  17301504   // 524288 + 16777216
#define LIST_B   17301536
#define RECI_B   17367072
#define RECF_B   18022432
#define NTILE (TT / TB)     // 1024

typedef short bf16x8 __attribute__((ext_vector_type(8)));
typedef float f32x4  __attribute__((ext_vector_type(4)));

__device__ __forceinline__ unsigned short f2bf(float x) {
    unsigned int u = __float_as_uint(x);
    u += 0x7FFFu + ((u >> 16) & 1u);
    return (unsigned short)(u >> 16);
}
__device__ __forceinline__ float bf2f(unsigned short b) {
    return __uint_as_float(((unsigned int)b) << 16);
}
__device__ __forceinline__ void cvt4(const float4 v, ushort4* hi, ushort4* lo) {
    unsigned short h0 = f2bf(v.x), h1 = f2bf(v.y),
                   h2 = f2bf(v.z), h3 = f2bf(v.w);
    *hi = make_ushort4(h0, h1, h2, h3);
    *lo = make_ushort4(f2bf(v.x - bf2f(h0)), f2bf(v.y - bf2f(h1)),
                       f2bf(v.z - bf2f(h2)), f2bf(v.w - bf2f(h3)));
}

__global__ __launch_bounds__(256)
void prep_kernel(const float* __restrict__ gw, unsigned short* __restrict__ ws,
                 unsigned int* __restrict__ nflag)
{
    if (blockIdx.x == 0 && threadIdx.x == 0) *nflag = 0u;   // replaces memset node
    const int gid = blockIdx.x * 256 + threadIdx.x;
    const int e  = gid >> 9;
    const int k  = (gid & 511) * 4;
    float4 v = *(const float4*)(gw + (size_t)e * HH + k);
    ushort4 hi, lo;
    cvt4(v, &hi, &lo);
    const int off = (k >> 5) * 2048 + ((k >> 3) & 3) * 512 + e * 8 + (k & 7);
    *(ushort4*)(ws + off)           = hi;
    *(ushort4*)(ws + WSPLANE + off) = lo;
}

#define CHUNKA(C, HV)                                                          \
  do {                                                                         \
    const unsigned short* bp_ = bBase + (size_t)(2 * (C)) * 2048;              \
    bf16x8 Bh0 = *(const bf16x8*)(bp_);                                        \
    bf16x8 Bl0 = *(const bf16x8*)(bp_ + WSPLANE);                              \
    bf16x8 Bh1 = *(const bf16x8*)(bp_ + 2048);                                 \
    bf16x8 Bl1 = *(const bf16x8*)(bp_ + 2048 + WSPLANE);                       \
    unsigned char* buf_ = smem + ((C) & 1) * 4096;                             \
    ushort4 hi_, lo_;                                                          \
    cvt4(HV, &hi_, &lo_);                                                      \
    *(ushort4*)(buf_ + hOff)        = hi_;                                     \
    *(ushort4*)(buf_ + 2048 + hOff) = lo_;                                     \
    __syncthreads();                                                           \
    if ((C) + 2 < climit) HV = *(const float4*)(hgp + ((C) + 2) * HC);         \
    bf16x8 Ah0 = *(const bf16x8*)(buf_ + aOff0);                               \
    bf16x8 Al0 = *(const bf16x8*)(buf_ + 2048 + aOff0);                        \
    bf16x8 Ah1 = *(const bf16x8*)(buf_ + aOff1);                               \
    bf16x8 Al1 = *(const bf16x8*)(buf_ + 2048 + aOff1);                        \
    acc = __builtin_amdgcn_mfma_f32_16x16x32_bf16(Ah0, Bl0, acc, 0, 0, 0);     \
    acc = __builtin_amdgcn_mfma_f32_16x16x32_bf16(Al0, Bh0, acc, 0, 0, 0);     \
    acc = __builtin_amdgcn_mfma_f32_16x16x32_bf16(Ah0, Bh0, acc, 0, 0, 0);     \
    acc = __builtin_amdgcn_mfma_f32_16x16x32_bf16(Ah1, Bl1, acc, 0, 0, 0);     \
    acc = __builtin_amdgcn_mfma_f32_16x16x32_bf16(Al1, Bh1, acc, 0, 0, 0);     \
    acc = __builtin_amdgcn_mfma_f32_16x16x32_bf16(Ah1, Bh1, acc, 0, 0, 0);     \
  } while (0)

__global__ __launch_bounds__(256, 8)
void gemm_partial(const float* __restrict__ hidden,
                  const unsigned short* __restrict__ wsbuf,
                  float* __restrict__ pbuf)
{
    __shared__ __align__(16) unsigned char smem[8192];

    const int tid  = threadIdx.x;
    const int bid  = blockIdx.x;
    const int tile = bid >> 2;         // KSPLIT=4
    const int ks   = bid & 3;
    const int tok0 = tile * TB;
    const int c0   = ks * CPS;
    const int climit = c0 + CPS;

    const int hr  = tid >> 4;
    const int hc4 = tid & 15;
    const float* hgp = hidden + (size_t)(tok0 + hr) * HH + hc4 * 4;
    const int hOff = hr * 128 + ((hc4 * 8) ^ ((hr & 7) << 4));

    const int lane = tid & 63;
    const int e0   = (tid >> 6) * 16;
    const int rx   = lane & 15;
    const int kq   = lane >> 4;
    const int aOff0 = rx * 128 + ((kq * 16) ^ ((rx & 7) << 4));
    const int aOff1 = aOff0 ^ 64;
    const unsigned short* bBase = wsbuf + kq * 512 + (e0 + rx) * 8;

    f32x4 acc = {0.f, 0.f, 0.f, 0.f};

    float4 hvA = *(const float4*)(hgp + c0 * HC);
    float4 hvB = *(const float4*)(hgp + (c0 + 1) * HC);

    for (int c = c0; c < climit; c += 2) {
        CHUNKA(c, hvA);
        CHUNKA(c + 1, hvB);
    }

    *(f32x4*)(pbuf + (size_t)bid * 1024 + tid * 4) = acc;
}

// ---- reduce + fp32 epilogue; flagged tokens -> record + compacted append ----
__global__ __launch_bounds__(256, 4)
void reduce_epilogue(const float* __restrict__ pbuf,
                     const float* __restrict__ bias,
                     unsigned int* __restrict__ nflag,
                     unsigned int* __restrict__ list,
                     int* __restrict__ recI,
                     float* __restrict__ recF,
                     float* __restrict__ out)
{
    __shared__ __align__(16) float lg[16 * 68 + 8];

    const int tid  = threadIdx.x;
    const int tile = blockIdx.x;
    const int tok0 = tile * TB;

    f32x4 a0 = *(const f32x4*)(pbuf + (size_t)(tile * 4 + 0) * 1024 + tid * 4);
    f32x4 a1 = *(const f32x4*)(pbuf + (size_t)(tile * 4 + 1) * 1024 + tid * 4);
    f32x4 a2 = *(const f32x4*)(pbuf + (size_t)(tile * 4 + 2) * 1024 + tid * 4);
    f32x4 a3 = *(const f32x4*)(pbuf + (size_t)(tile * 4 + 3) * 1024 + tid * 4);
    f32x4 acc = (a0 + a1) + (a2 + a3);

    const int lane = tid & 63;
    const int e0   = (tid >> 6) * 16;
    const int rx   = lane & 15;
    const int kq   = lane >> 4;

    #pragma unroll
    for (int r = 0; r < 4; ++r)
        lg[(4 * kq + r) * 68 + e0 + rx] = acc[r];
    __syncthreads();

    const int t   = tid >> 4;
    const int q   = tid & 15;
    const int tok = tok0 + t;

    float lv[4];
    #pragma unroll
    for (int i = 0; i < 4; ++i) lv[i] = lg[t * 68 + q + 16 * i];

    float mx = lv[0];
    #pragma unroll
    for (int i = 1; i < 4; ++i) mx = fmaxf(mx, lv[i]);
    #pragma unroll
    for (int sh = 1; sh < 16; sh <<= 1) mx = fmaxf(mx, __shfl_xor(mx, sh, 64));

    float ex[4], psum = 0.0f;
    #pragma unroll
    for (int i = 0; i < 4; ++i) { ex[i] = expf(lv[i] - mx); psum += ex[i]; }
    #pragma unroll
    for (int sh = 1; sh < 16; sh <<= 1) psum += __shfl_xor(psum, sh, 64);
    const float inv = 1.0f / psum;

    float pr[4], selv[4];
    #pragma unroll
    for (int i = 0; i < 4; ++i) {
        pr[i]   = ex[i] * inv;
        selv[i] = pr[i] + bias[q + 16 * i];
    }

    float ws_[TOPC], wp[TOPC];
    int   wi[TOPC];
    #pragma unroll
    for (int k = 0; k < TOPC; ++k) {
        float bs = selv[0], bp = pr[0];
        int bi = q;
        #pragma unroll
        for (int i = 1; i < 4; ++i)
            if (selv[i] > bs) { bs = selv[i]; bp = pr[i]; bi = q + 16 * i; }
        #pragma unroll
        for (int sh = 1; sh < 16; sh <<= 1) {
            float os = __shfl_xor(bs, sh, 64);
            float op = __shfl_xor(bp, sh, 64);
            int   ob = __shfl_xor(bi, sh, 64);
            if (os > bs || (os == bs && ob < bi)) { bs = os; bp = op; bi = ob; }
        }
        ws_[k] = bs; wp[k] = bp; wi[k] = bi;
        #pragma unroll
        for (int i = 0; i < 4; ++i)
            if (q + 16 * i == bi) selv[i] = -INFINITY;
    }

    bool flag = false;
    #pragma unroll
    for (int k = 0; k < 8; ++k)
        flag = flag || (ws_[k] - ws_[k + 1] <
                        (ws_[k] + ws_[k + 1]) * MARGIN_REL + 1e-12f);

    {
        int   mywi = wi[0];
        float mywp = wp[0];
        #pragma unroll
        for (int k = 1; k < TOPC; ++k)
            if (q == k) { mywi = wi[k]; mywp = wp[k]; }
        if (flag && q < TOPC) {
            recI[(size_t)tok * 10 + q] = mywi;
            recF[(size_t)tok * 12 + q] = mywp;
        }
        if (flag && q == 0) {
            recF[(size_t)tok * 12 + 10] = mx;
            recF[(size_t)tok * 12 + 11] = inv;
            unsigned int o = atomicAdd(nflag, 1u);
            list[o] = (unsigned int)tok;
        }
    }

    int oi = wi[0];
    float opf = wp[0];
    #pragma unroll
    for (int k = 1; k < 8; ++k)
        if (q == k) { oi = wi[k]; opf = wp[k]; }

    float ps = 0.0f;
    #pragma unroll
    for (int k = 0; k < 8; ++k) ps += wp[k];
    const float rinv = 1.0f / (ps + 1e-9f);

    if (q < KK) {
        out[(size_t)tok * KK + q]           = opf * rinv;
        out[IDX_OFF + (size_t)tok * KK + q] = (float)oi;
    }

    unsigned long long mk = 0ull;
    #pragma unroll
    for (int k = 0; k < 8; ++k) mk |= (1ull << wi[k]);

    {
        float4 a;
        a.x = ((mk >> (4 * q + 0)) & 1ull) ? 1.0f : 0.0f;
        a.y = ((mk >> (4 * q + 1)) & 1ull) ? 1.0f : 0.0f;
        a.z = ((mk >> (4 * q + 2)) & 1ull) ? 1.0f : 0.0f;
        a.w = ((mk >> (4 * q + 3)) & 1ull) ? 1.0f : 0.0f;
        *(float4*)(out + MAP_OFF + (size_t)tok * EE + 4 * q) = a;
    }

    if (tile == 0 && tid == 0) out[AUX_OFF] = 0.0f;
}

// ---- fixup: one 256-thread block per flagged token (grid-stride list) ----
__global__ __launch_bounds__(256, 4)
void fixup_kernel(const float* __restrict__ hidden,
                  const float* __restrict__ gate_w,
                  const float* __restrict__ bias,
                  const unsigned int* __restrict__ nflag,
                  const unsigned int* __restrict__ list,
                  const int* __restrict__ recI,
                  const float* __restrict__ recF,
                  float* __restrict__ out)
{
    __shared__ double redL[4][12];

    const int tid  = threadIdx.x;
    const int wv   = tid >> 6;
    const int lane = tid & 63;
    const unsigned int nf = *nflag;

    for (unsigned int i = blockIdx.x; i < nf; i += gridDim.x) {
        const int tok = (int)list[i];

        int   wk[TOPC];
        #pragma unroll
        for (int k = 0; k < TOPC; ++k) wk[k] = recI[(size_t)tok * 10 + k];
        const float mx  = recF[(size_t)tok * 12 + 10];
        const float inv = recF[(size_t)tok * 12 + 11];

        const float* hp = hidden + (size_t)tok * HH + tid * 8;
        float4 ha = *(const float4*)(hp);
        float4 hb = *(const float4*)(hp + 4);
        double h0 = ha.x, h1 = ha.y, h2 = ha.z, h3 = ha.w;
        double h4 = hb.x, h5 = hb.y, h6 = hb.z, h7 = hb.w;

        double l64[TOPC];
        #pragma unroll
        for (int k = 0; k < TOPC; ++k) {
            const float* wpt = gate_w + (size_t)wk[k] * HH + tid * 8;
            float4 wa = *(const float4*)(wpt);
            float4 wb = *(const float4*)(wpt + 4);
            double s = 0.0;
            s = fma(h0, (double)wa.x, s); s = fma(h1, (double)wa.y, s);
            s = fma(h2, (double)wa.z, s); s = fma(h3, (double)wa.w, s);
            s = fma(h4, (double)wb.x, s); s = fma(h5, (double)wb.y, s);
            s = fma(h6, (double)wb.z, s); s = fma(h7, (double)wb.w, s);
            l64[k] = s;
        }
        #pragma unroll
        for (int k = 0; k < TOPC; ++k)
            #pragma unroll
            for (int sh = 1; sh < 64; sh <<= 1)
                l64[k] += __shfl_xor(l64[k], sh, 64);
        if (lane == 0)
            #pragma unroll
            for (int k = 0; k < TOPC; ++k) redL[wv][k] = l64[k];
        __syncthreads();

        if (tid == 0) {
            double s64[TOPC];
            int    wi2[TOPC];
            float  wp2[TOPC];
            #pragma unroll
            for (int k = 0; k < TOPC; ++k) {
                double lk = redL[0][k] + redL[1][k] + redL[2][k] + redL[3][k];
                s64[k] = exp(lk - (double)mx) * (double)inv +
                         (double)bias[wk[k]];
                wi2[k] = wk[k];
                wp2[k] = recF[(size_t)tok * 12 + k];
            }
            #pragma unroll
            for (int a = 0; a < 8; ++a) {
                #pragma unroll
                for (int b = a + 1; b < TOPC; ++b) {
                    bool sw = (s64[b] > s64[a]) ||
                              (s64[b] == s64[a] && wi2[b] < wi2[a]);
                    if (sw) {
                        double td = s64[a]; s64[a] = s64[b]; s64[b] = td;
                        int    ti = wi2[a]; wi2[a] = wi2[b]; wi2[b] = ti;
                        float  tp = wp2[a]; wp2[a] = wp2[b]; wp2[b] = tp;
                    }
                }
            }
            float ps = 0.0f;
            #pragma unroll
            for (int k = 0; k < 8; ++k) ps += wp2[k];
            const float rinv = 1.0f / (ps + 1e-9f);
            unsigned long long mk = 0ull;
            #pragma unroll
            for (int k = 0; k < 8; ++k) {
                out[(size_t)tok * KK + k]           = wp2[k] * rinv;
                out[IDX_OFF + (size_t)tok * KK + k] = (float)wi2[k];
                mk |= (1ull << wi2[k]);
            }
            for (int e = 0; e < EE; ++e)
                out[MAP_OFF + (size_t)tok * EE + e] =
                    ((mk >> e) & 1ull) ? 1.0f : 0.0f;
        }
        __syncthreads();
    }
}

extern "C" void kernel_launch(void* const* d_in, const int* in_sizes, int n_in,
                              void* d_out, int out_size, void* d_ws, size_t ws_size,
                              hipStream_t stream) {
    const float* hidden = (const float*)d_in[0];
    const float* gate_w = (const float*)d_in[1];
    const float* bias   = (const float*)d_in[2];
    float* out = (float*)d_out;

    char* wsb = (char*)d_ws;
    unsigned short* wplanes = (unsigned short*)wsb;
    float*        pbuf  = (float*)(wsb + PBUF_B);
    unsigned int* nflag = (unsigned int*)(wsb + NFLAG_B);
    unsigned int* list  = (unsigned int*)(wsb + LIST_B);
    int*          recI  = (int*)(wsb + RECI_B);
    float*        recF  = (float*)(wsb + RECF_B);

    prep_kernel<<<128, 256, 0, stream>>>(gate_w, wplanes, nflag);
    gemm_partial<<<NTILE * KSPLIT, 256, 0, stream>>>(hidden, wplanes, pbuf);
    reduce_epilogue<<<NTILE, 256, 0, stream>>>(pbuf, bias, nflag, list,
                                               recI, recF, out);
    fixup_kernel<<<256, 256, 0, stream>>>(hidden, gate_w, bias, nflag, list,
                                          recI, recF, out);
}

// Round 19
// 62.103 us; speedup vs baseline: 9.2603x; 1.0504x over previous
//
#include <hip/hip_runtime.h>
#include <math.h>

// Problem constants
#define TT 16384
#define HH 2048
#define EE 64
#define KK 8

#define TB 16
#define HC 64
#define NCH (HH / HC)        // 32 chunks
#define KSPLIT 4             // one wave per K-slice
#define CPS (NCH / KSPLIT)   // 8 chunks per slice
#define TOPC 10
#define MARGIN_REL 8e-5f

// Output layout (flat float32):
#define IDX_OFF ((size_t)TT * KK)
#define MAP_OFF ((size_t)2 * TT * KK)
#define AUX_OFF ((size_t)2 * TT * KK + (size_t)TT * EE)

// d_ws byte layout: W planes | nflag | list | recI | recF  (~2 MB total)
#define WSPLANE 131072
#define NFLAG_B  524288
#define LIST_B   524320
#define RECI_B   589856
#define RECF_B   1245216
#define NTILE (TT / TB)      // 1024

typedef short bf16x8 __attribute__((ext_vector_type(8)));
typedef float f32x4  __attribute__((ext_vector_type(4)));

__device__ __forceinline__ unsigned short f2bf(float x) {
    unsigned int u = __float_as_uint(x);
    u += 0x7FFFu + ((u >> 16) & 1u);
    return (unsigned short)(u >> 16);
}
__device__ __forceinline__ float bf2f(unsigned short b) {
    return __uint_as_float(((unsigned int)b) << 16);
}
__device__ __forceinline__ void cvt4(const float4 v, ushort4* hi, ushort4* lo) {
    unsigned short h0 = f2bf(v.x), h1 = f2bf(v.y),
                   h2 = f2bf(v.z), h3 = f2bf(v.w);
    *hi = make_ushort4(h0, h1, h2, h3);
    *lo = make_ushort4(f2bf(v.x - bf2f(h0)), f2bf(v.y - bf2f(h1)),
                       f2bf(v.z - bf2f(h2)), f2bf(v.w - bf2f(h3)));
}

__global__ __launch_bounds__(256)
void prep_kernel(const float* __restrict__ gw, unsigned short* __restrict__ ws,
                 unsigned int* __restrict__ nflag)
{
    if (blockIdx.x == 0 && threadIdx.x == 0) *nflag = 0u;
    const int gid = blockIdx.x * 256 + threadIdx.x;
    const int e  = gid >> 9;
    const int k  = (gid & 511) * 4;
    float4 v = *(const float4*)(gw + (size_t)e * HH + k);
    ushort4 hi, lo;
    cvt4(v, &hi, &lo);
    const int off = (k >> 5) * 2048 + ((k >> 3) & 3) * 512 + e * 8 + (k & 7);
    *(ushort4*)(ws + off)           = hi;
    *(ushort4*)(ws + WSPLANE + off) = lo;
}

// 3 MFMA (bf16x3) into acc##ET from B tile ET (u=0: UOFF=0, u=1: UOFF=2048)
#define MM(ET, AH, AL, BP, UOFF)                                               \
  {                                                                            \
    bf16x8 Bh = *(const bf16x8*)((BP) + (UOFF) + (ET) * 128);                  \
    bf16x8 Bl = *(const bf16x8*)((BP) + (UOFF) + (ET) * 128 + WSPLANE);        \
    acc##ET = __builtin_amdgcn_mfma_f32_16x16x32_bf16(AH, Bl, acc##ET, 0,0,0); \
    acc##ET = __builtin_amdgcn_mfma_f32_16x16x32_bf16(AL, Bh, acc##ET, 0,0,0); \
    acc##ET = __builtin_amdgcn_mfma_f32_16x16x32_bf16(AH, Bh, acc##ET, 0,0,0); \
  }

// Wave-synchronous chunk: stage 4 slots, prefetch C+2, 2 k-steps x 4 tiles.
// No __syncthreads — per-wave LDS ops are in-order; lgkmcnt handles RAW.
#define CHUNKW(C, A0, A1, A2, A3)                                              \
  do {                                                                         \
    unsigned char* buf_ = wbuf + ((C) & 1) * 4096;                             \
    ushort4 hi_, lo_;                                                          \
    cvt4(A0, &hi_, &lo_);                                                      \
    *(ushort4*)(buf_ + wOff0) = hi_; *(ushort4*)(buf_ + 2048 + wOff0) = lo_;   \
    cvt4(A1, &hi_, &lo_);                                                      \
    *(ushort4*)(buf_ + wOff1) = hi_; *(ushort4*)(buf_ + 2048 + wOff1) = lo_;   \
    cvt4(A2, &hi_, &lo_);                                                      \
    *(ushort4*)(buf_ + wOff2) = hi_; *(ushort4*)(buf_ + 2048 + wOff2) = lo_;   \
    cvt4(A3, &hi_, &lo_);                                                      \
    *(ushort4*)(buf_ + wOff3) = hi_; *(ushort4*)(buf_ + 2048 + wOff3) = lo_;   \
    if ((C) + 2 < CPS) {                                                       \
      const float* hp_ = hgp + (c0 + (C) + 2) * HC;                            \
      A0 = *(const float4*)(hp_);      A1 = *(const float4*)(hp_ + 16);        \
      A2 = *(const float4*)(hp_ + 32); A3 = *(const float4*)(hp_ + 48);        \
    }                                                                          \
    const unsigned short* bp_ = bBase + (size_t)(2 * (c0 + (C))) * 2048;       \
    {                                                                          \
      bf16x8 Ah = *(const bf16x8*)(buf_ + aOff0);                              \
      bf16x8 Al = *(const bf16x8*)(buf_ + 2048 + aOff0);                       \
      MM(0, Ah, Al, bp_, 0) MM(1, Ah, Al, bp_, 0)                              \
      MM(2, Ah, Al, bp_, 0) MM(3, Ah, Al, bp_, 0)                              \
    }                                                                          \
    {                                                                          \
      bf16x8 Ah = *(const bf16x8*)(buf_ + aOff1);                              \
      bf16x8 Al = *(const bf16x8*)(buf_ + 2048 + aOff1);                       \
      MM(0, Ah, Al, bp_, 2048) MM(1, Ah, Al, bp_, 2048)                        \
      MM(2, Ah, Al, bp_, 2048) MM(3, Ah, Al, bp_, 2048)                        \
    }                                                                          \
  } while (0)

__global__ __launch_bounds__(256, 4)
void fused_gemm(const float* __restrict__ hidden,
                const float* __restrict__ bias,
                const unsigned short* __restrict__ wsbuf,
                unsigned int* __restrict__ nflag,
                unsigned int* __restrict__ list,
                int* __restrict__ recI,
                float* __restrict__ recF,
                float* __restrict__ out)
{
    // per-wave dbuf staging: 4 waves x 2 x 4096 B = 32 KB (red overlays after)
    __shared__ __align__(16) unsigned char smem[32768];

    const int tid  = threadIdx.x;
    const int w    = tid >> 6;       // wave = K-slice
    const int lane = tid & 63;
    const int tile = blockIdx.x;
    const int tok0 = tile * TB;
    const int c0   = w * CPS;        // slice's first chunk

    // staging coords: lane stages row hr, slots q4+4j (j=0..3)
    const int hr = lane >> 2;        // 0..15
    const int q4 = lane & 3;
    const float* hgp = hidden + (size_t)(tok0 + hr) * HH + q4 * 4;
    unsigned char* wbuf = smem + w * 8192;
    const int key = (hr & 7) << 4;
    const int wOff0 = hr * 128 + (((q4 + 0)  * 8) ^ key);
    const int wOff1 = hr * 128 + (((q4 + 4)  * 8) ^ key);
    const int wOff2 = hr * 128 + (((q4 + 8)  * 8) ^ key);
    const int wOff3 = hr * 128 + (((q4 + 12) * 8) ^ key);

    // fragment coords (R14-validated formulas, wave-local buffer)
    const int rx = lane & 15;
    const int kq = lane >> 4;
    const int aOff0 = rx * 128 + ((kq * 16) ^ ((rx & 7) << 4));
    const int aOff1 = aOff0 ^ 64;
    const unsigned short* bBase = wsbuf + kq * 512 + rx * 8;

    f32x4 acc0 = {0.f,0.f,0.f,0.f}, acc1 = {0.f,0.f,0.f,0.f};
    f32x4 acc2 = {0.f,0.f,0.f,0.f}, acc3 = {0.f,0.f,0.f,0.f};

    // 2-deep prefetch ring (static names)
    float4 a0, a1, a2, a3, b0, b1, b2, b3;
    {
        const float* hp = hgp + c0 * HC;
        a0 = *(const float4*)(hp);      a1 = *(const float4*)(hp + 16);
        a2 = *(const float4*)(hp + 32); a3 = *(const float4*)(hp + 48);
        const float* hq = hgp + (c0 + 1) * HC;
        b0 = *(const float4*)(hq);      b1 = *(const float4*)(hq + 16);
        b2 = *(const float4*)(hq + 32); b3 = *(const float4*)(hq + 48);
    }

    for (int c = 0; c < CPS; c += 2) {
        CHUNKW(c,     a0, a1, a2, a3);
        CHUNKW(c + 1, b0, b1, b2, b3);
    }

    // ---- cross-wave reduce: partials to LDS overlay ----
    __syncthreads();                  // all waves done with staging buffers
    float* red = (float*)smem;        // [4 waves][16 tok][68] = 17408 B
    {
        float* rw = red + w * 1088;
        #pragma unroll
        for (int r = 0; r < 4; ++r) {
            const int row = (4 * kq + r) * 68 + rx;
            rw[row +  0] = acc0[r];
            rw[row + 16] = acc1[r];
            rw[row + 32] = acc2[r];
            rw[row + 48] = acc3[r];
        }
    }
    __syncthreads();

    // ---- epilogue: 16 lanes per token (R17/R18-validated) ----
    const int t   = tid >> 4;
    const int q   = tid & 15;
    const int tok = tok0 + t;

    float lv[4];
    #pragma unroll
    for (int i = 0; i < 4; ++i) {
        const int o = t * 68 + q + 16 * i;
        lv[i] = (red[o] + red[1088 + o]) + (red[2176 + o] + red[3264 + o]);
    }

    float mx = lv[0];
    #pragma unroll
    for (int i = 1; i < 4; ++i) mx = fmaxf(mx, lv[i]);
    #pragma unroll
    for (int sh = 1; sh < 16; sh <<= 1) mx = fmaxf(mx, __shfl_xor(mx, sh, 64));

    float ex[4], psum = 0.0f;
    #pragma unroll
    for (int i = 0; i < 4; ++i) { ex[i] = expf(lv[i] - mx); psum += ex[i]; }
    #pragma unroll
    for (int sh = 1; sh < 16; sh <<= 1) psum += __shfl_xor(psum, sh, 64);
    const float inv = 1.0f / psum;

    float pr[4], selv[4];
    #pragma unroll
    for (int i = 0; i < 4; ++i) {
        pr[i]   = ex[i] * inv;
        selv[i] = pr[i] + bias[q + 16 * i];
    }

    float ws_[TOPC], wp[TOPC];
    int   wi[TOPC];
    #pragma unroll
    for (int k = 0; k < TOPC; ++k) {
        float bs = selv[0], bp = pr[0];
        int bi = q;
        #pragma unroll
        for (int i = 1; i < 4; ++i)
            if (selv[i] > bs) { bs = selv[i]; bp = pr[i]; bi = q + 16 * i; }
        #pragma unroll
        for (int sh = 1; sh < 16; sh <<= 1) {
            float os = __shfl_xor(bs, sh, 64);
            float op = __shfl_xor(bp, sh, 64);
            int   ob = __shfl_xor(bi, sh, 64);
            if (os > bs || (os == bs && ob < bi)) { bs = os; bp = op; bi = ob; }
        }
        ws_[k] = bs; wp[k] = bp; wi[k] = bi;
        #pragma unroll
        for (int i = 0; i < 4; ++i)
            if (q + 16 * i == bi) selv[i] = -INFINITY;
    }

    bool flag = false;
    #pragma unroll
    for (int k = 0; k < 8; ++k)
        flag = flag || (ws_[k] - ws_[k + 1] <
                        (ws_[k] + ws_[k + 1]) * MARGIN_REL + 1e-12f);

    {
        int   mywi = wi[0];
        float mywp = wp[0];
        #pragma unroll
        for (int k = 1; k < TOPC; ++k)
            if (q == k) { mywi = wi[k]; mywp = wp[k]; }
        if (flag && q < TOPC) {
            recI[(size_t)tok * 10 + q] = mywi;
            recF[(size_t)tok * 12 + q] = mywp;
        }
        if (flag && q == 0) {
            recF[(size_t)tok * 12 + 10] = mx;
            recF[(size_t)tok * 12 + 11] = inv;
            unsigned int o = atomicAdd(nflag, 1u);
            list[o] = (unsigned int)tok;
        }
    }

    int oi = wi[0];
    float opf = wp[0];
    #pragma unroll
    for (int k = 1; k < 8; ++k)
        if (q == k) { oi = wi[k]; opf = wp[k]; }

    float ps = 0.0f;
    #pragma unroll
    for (int k = 0; k < 8; ++k) ps += wp[k];
    const float rinv = 1.0f / (ps + 1e-9f);

    if (q < KK) {
        out[(size_t)tok * KK + q]           = opf * rinv;
        out[IDX_OFF + (size_t)tok * KK + q] = (float)oi;
    }

    unsigned long long mk = 0ull;
    #pragma unroll
    for (int k = 0; k < 8; ++k) mk |= (1ull << wi[k]);

    {
        float4 a;
        a.x = ((mk >> (4 * q + 0)) & 1ull) ? 1.0f : 0.0f;
        a.y = ((mk >> (4 * q + 1)) & 1ull) ? 1.0f : 0.0f;
        a.z = ((mk >> (4 * q + 2)) & 1ull) ? 1.0f : 0.0f;
        a.w = ((mk >> (4 * q + 3)) & 1ull) ? 1.0f : 0.0f;
        *(float4*)(out + MAP_OFF + (size_t)tok * EE + 4 * q) = a;
    }

    if (tile == 0 && tid == 0) out[AUX_OFF] = 0.0f;
}

// ---- fixup: one 256-thread block per flagged token (R17-validated) ----
__global__ __launch_bounds__(256, 4)
void fixup_kernel(const float* __restrict__ hidden,
                  const float* __restrict__ gate_w,
                  const float* __restrict__ bias,
                  const unsigned int* __restrict__ nflag,
                  const unsigned int* __restrict__ list,
                  const int* __restrict__ recI,
                  const float* __restrict__ recF,
                  float* __restrict__ out)
{
    __shared__ double redL[4][12];

    const int tid  = threadIdx.x;
    const int wv   = tid >> 6;
    const int lane = tid & 63;
    const unsigned int nf = *nflag;

    for (unsigned int i = blockIdx.x; i < nf; i += gridDim.x) {
        const int tok = (int)list[i];

        int   wk[TOPC];
        #pragma unroll
        for (int k = 0; k < TOPC; ++k) wk[k] = recI[(size_t)tok * 10 + k];
        const float mx  = recF[(size_t)tok * 12 + 10];
        const float inv = recF[(size_t)tok * 12 + 11];

        const float* hp = hidden + (size_t)tok * HH + tid * 8;
        float4 ha = *(const float4*)(hp);
        float4 hb = *(const float4*)(hp + 4);
        double h0 = ha.x, h1 = ha.y, h2 = ha.z, h3 = ha.w;
        double h4 = hb.x, h5 = hb.y, h6 = hb.z, h7 = hb.w;

        double l64[TOPC];
        #pragma unroll
        for (int k = 0; k < TOPC; ++k) {
            const float* wpt = gate_w + (size_t)wk[k] * HH + tid * 8;
            float4 wa = *(const float4*)(wpt);
            float4 wb = *(const float4*)(wpt + 4);
            double s = 0.0;
            s = fma(h0, (double)wa.x, s); s = fma(h1, (double)wa.y, s);
            s = fma(h2, (double)wa.z, s); s = fma(h3, (double)wa.w, s);
            s = fma(h4, (double)wb.x, s); s = fma(h5, (double)wb.y, s);
            s = fma(h6, (double)wb.z, s); s = fma(h7, (double)wb.w, s);
            l64[k] = s;
        }
        #pragma unroll
        for (int k = 0; k < TOPC; ++k)
            #pragma unroll
            for (int sh = 1; sh < 64; sh <<= 1)
                l64[k] += __shfl_xor(l64[k], sh, 64);
        if (lane == 0)
            #pragma unroll
            for (int k = 0; k < TOPC; ++k) redL[wv][k] = l64[k];
        __syncthreads();

        if (tid == 0) {
            double s64[TOPC];
            int    wi2[TOPC];
            float  wp2[TOPC];
            #pragma unroll
            for (int k = 0; k < TOPC; ++k) {
                double lk = redL[0][k] + redL[1][k] + redL[2][k] + redL[3][k];
                s64[k] = exp(lk - (double)mx) * (double)inv +
                         (double)bias[wk[k]];
                wi2[k] = wk[k];
                wp2[k] = recF[(size_t)tok * 12 + k];
            }
            #pragma unroll
            for (int a = 0; a < 8; ++a) {
                #pragma unroll
                for (int b = a + 1; b < TOPC; ++b) {
                    bool sw = (s64[b] > s64[a]) ||
                              (s64[b] == s64[a] && wi2[b] < wi2[a]);
                    if (sw) {
                        double td = s64[a]; s64[a] = s64[b]; s64[b] = td;
                        int    ti = wi2[a]; wi2[a] = wi2[b]; wi2[b] = ti;
                        float  tp = wp2[a]; wp2[a] = wp2[b]; wp2[b] = tp;
                    }
                }
            }
            float ps = 0.0f;
            #pragma unroll
            for (int k = 0; k < 8; ++k) ps += wp2[k];
            const float rinv = 1.0f / (ps + 1e-9f);
            unsigned long long mk = 0ull;
            #pragma unroll
            for (int k = 0; k < 8; ++k) {
                out[(size_t)tok * KK + k]           = wp2[k] * rinv;
                out[IDX_OFF + (size_t)tok * KK + k] = (float)wi2[k];
                mk |= (1ull << wi2[k]);
            }
            for (int e = 0; e < EE; ++e)
                out[MAP_OFF + (size_t)tok * EE + e] =
                    ((mk >> e) & 1ull) ? 1.0f : 0.0f;
        }
        __syncthreads();
    }
}

extern "C" void kernel_launch(void* const* d_in, const int* in_sizes, int n_in,
                              void* d_out, int out_size, void* d_ws, size_t ws_size,
                              hipStream_t stream) {
    const float* hidden = (const float*)d_in[0];
    const float* gate_w = (const float*)d_in[1];
    const float* bias   = (const float*)d_in[2];
    float* out = (float*)d_out;

    char* wsb = (char*)d_ws;
    unsigned short* wplanes = (unsigned short*)wsb;
    unsigned int* nflag = (unsigned int*)(wsb + NFLAG_B);
    unsigned int* list  = (unsigned int*)(wsb + LIST_B);
    int*          recI  = (int*)(wsb + RECI_B);
    float*        recF  = (float*)(wsb + RECF_B);

    prep_kernel<<<128, 256, 0, stream>>>(gate_w, wplanes, nflag);
    fused_gemm<<<NTILE, 256, 0, stream>>>(hidden, bias, wplanes, nflag, list,
                                          recI, recF, out);
    fixup_kernel<<<256, 256, 0, stream>>>(hidden, gate_w, bias, nflag, list,
                                          recI, recF, out);
}

// Round 20
// 61.742 us; speedup vs baseline: 9.3145x; 1.0059x over previous
//
#include <hip/hip_runtime.h>
#include <math.h>

// Problem constants
#define TT 16384
#define HH 2048
#define EE 64
#define KK 8

#define TB 32                // tokens per block (2 token-halves x 16)
#define HC 64
#define NCH (HH / HC)        // 32 chunks
#define KSPLIT 4             // K-slices (one per wave-pair)
#define CPS (NCH / KSPLIT)   // 8 chunks per slice
#define TOPC 10
#define MARGIN_REL 8e-5f

// Output layout (flat float32):
#define IDX_OFF ((size_t)TT * KK)
#define MAP_OFF ((size_t)2 * TT * KK)
#define AUX_OFF ((size_t)2 * TT * KK + (size_t)TT * EE)

// d_ws byte layout: W planes | nflag | list | recI | recF  (~2 MB total)
#define WSPLANE 131072
#define NFLAG_B  524288
#define LIST_B   524320
#define RECI_B   589856
#define RECF_B   1245216
#define NTILE (TT / TB)      // 512

typedef short bf16x8 __attribute__((ext_vector_type(8)));
typedef float f32x4  __attribute__((ext_vector_type(4)));

__device__ __forceinline__ unsigned short f2bf(float x) {
    unsigned int u = __float_as_uint(x);
    u += 0x7FFFu + ((u >> 16) & 1u);
    return (unsigned short)(u >> 16);
}
__device__ __forceinline__ float bf2f(unsigned short b) {
    return __uint_as_float(((unsigned int)b) << 16);
}
__device__ __forceinline__ void cvt4(const float4 v, ushort4* hi, ushort4* lo) {
    unsigned short h0 = f2bf(v.x), h1 = f2bf(v.y),
                   h2 = f2bf(v.z), h3 = f2bf(v.w);
    *hi = make_ushort4(h0, h1, h2, h3);
    *lo = make_ushort4(f2bf(v.x - bf2f(h0)), f2bf(v.y - bf2f(h1)),
                       f2bf(v.z - bf2f(h2)), f2bf(v.w - bf2f(h3)));
}

__global__ __launch_bounds__(256)
void prep_kernel(const float* __restrict__ gw, unsigned short* __restrict__ ws,
                 unsigned int* __restrict__ nflag)
{
    if (blockIdx.x == 0 && threadIdx.x == 0) *nflag = 0u;
    const int gid = blockIdx.x * 256 + threadIdx.x;
    const int e  = gid >> 9;
    const int k  = (gid & 511) * 4;
    float4 v = *(const float4*)(gw + (size_t)e * HH + k);
    ushort4 hi, lo;
    cvt4(v, &hi, &lo);
    const int off = (k >> 5) * 2048 + ((k >> 3) & 3) * 512 + e * 8 + (k & 7);
    *(ushort4*)(ws + off)           = hi;
    *(ushort4*)(ws + WSPLANE + off) = lo;
}

// 3 MFMA (bf16x3) into acc##ET from B tile ET (u=0: UOFF=0, u=1: UOFF=2048)
#define MM(ET, AH, AL, BP, UOFF)                                               \
  {                                                                            \
    bf16x8 Bh = *(const bf16x8*)((BP) + (UOFF) + (ET) * 128);                  \
    bf16x8 Bl = *(const bf16x8*)((BP) + (UOFF) + (ET) * 128 + WSPLANE);        \
    acc##ET = __builtin_amdgcn_mfma_f32_16x16x32_bf16(AH, Bl, acc##ET, 0,0,0); \
    acc##ET = __builtin_amdgcn_mfma_f32_16x16x32_bf16(AL, Bh, acc##ET, 0,0,0); \
    acc##ET = __builtin_amdgcn_mfma_f32_16x16x32_bf16(AH, Bh, acc##ET, 0,0,0); \
  }

// Wave-synchronous chunk (R19-validated): stage 4 slots, prefetch C+2,
// 2 k-steps x 4 expert tiles. No __syncthreads — per-wave LDS ops in-order.
#define CHUNKW(C, A0, A1, A2, A3)                                              \
  do {                                                                         \
    unsigned char* buf_ = wbuf + ((C) & 1) * 4096;                             \
    ushort4 hi_, lo_;                                                          \
    cvt4(A0, &hi_, &lo_);                                                      \
    *(ushort4*)(buf_ + wOff0) = hi_; *(ushort4*)(buf_ + 2048 + wOff0) = lo_;   \
    cvt4(A1, &hi_, &lo_);                                                      \
    *(ushort4*)(buf_ + wOff1) = hi_; *(ushort4*)(buf_ + 2048 + wOff1) = lo_;   \
    cvt4(A2, &hi_, &lo_);                                                      \
    *(ushort4*)(buf_ + wOff2) = hi_; *(ushort4*)(buf_ + 2048 + wOff2) = lo_;   \
    cvt4(A3, &hi_, &lo_);                                                      \
    *(ushort4*)(buf_ + wOff3) = hi_; *(ushort4*)(buf_ + 2048 + wOff3) = lo_;   \
    if ((C) + 2 < CPS) {                                                       \
      const float* hp_ = hgp + (c0 + (C) + 2) * HC;                            \
      A0 = *(const float4*)(hp_);      A1 = *(const float4*)(hp_ + 16);        \
      A2 = *(const float4*)(hp_ + 32); A3 = *(const float4*)(hp_ + 48);        \
    }                                                                          \
    const unsigned short* bp_ = bBase + (size_t)(2 * (c0 + (C))) * 2048;       \
    {                                                                          \
      bf16x8 Ah = *(const bf16x8*)(buf_ + aOff0);                              \
      bf16x8 Al = *(const bf16x8*)(buf_ + 2048 + aOff0);                       \
      MM(0, Ah, Al, bp_, 0) MM(1, Ah, Al, bp_, 0)                              \
      MM(2, Ah, Al, bp_, 0) MM(3, Ah, Al, bp_, 0)                              \
    }                                                                          \
    {                                                                          \
      bf16x8 Ah = *(const bf16x8*)(buf_ + aOff1);                              \
      bf16x8 Al = *(const bf16x8*)(buf_ + 2048 + aOff1);                       \
      MM(0, Ah, Al, bp_, 2048) MM(1, Ah, Al, bp_, 2048)                        \
      MM(2, Ah, Al, bp_, 2048) MM(3, Ah, Al, bp_, 2048)                        \
    }                                                                          \
  } while (0)

__global__ __launch_bounds__(512, 4)
void fused_gemm(const float* __restrict__ hidden,
                const float* __restrict__ bias,
                const unsigned short* __restrict__ wsbuf,
                unsigned int* __restrict__ nflag,
                unsigned int* __restrict__ list,
                int* __restrict__ recI,
                float* __restrict__ recF,
                float* __restrict__ out)
{
    // per-wave dbuf staging: 8 waves x 8192 B = 64 KB (red overlays after)
    __shared__ __align__(16) unsigned char smem[65536];

    const int tid  = threadIdx.x;
    const int w    = tid >> 6;       // 0..7
    const int g    = w >> 2;         // token-half 0/1
    const int s    = w & 3;          // K-slice
    const int lane = tid & 63;
    const int tile = blockIdx.x;
    const int tok0 = tile * TB;
    const int c0   = s * CPS;

    // staging coords: lane stages row hr (of this wave's 16-token half)
    const int hr = lane >> 2;        // 0..15
    const int q4 = lane & 3;
    const float* hgp = hidden + (size_t)(tok0 + g * 16 + hr) * HH + q4 * 4;
    unsigned char* wbuf = smem + w * 8192;
    const int key = (hr & 7) << 4;
    const int wOff0 = hr * 128 + (((q4 + 0)  * 8) ^ key);
    const int wOff1 = hr * 128 + (((q4 + 4)  * 8) ^ key);
    const int wOff2 = hr * 128 + (((q4 + 8)  * 8) ^ key);
    const int wOff3 = hr * 128 + (((q4 + 12) * 8) ^ key);

    // fragment coords (R14-validated formulas, wave-local buffer)
    const int rx = lane & 15;
    const int kq = lane >> 4;
    const int aOff0 = rx * 128 + ((kq * 16) ^ ((rx & 7) << 4));
    const int aOff1 = aOff0 ^ 64;
    const unsigned short* bBase = wsbuf + kq * 512 + rx * 8;

    f32x4 acc0 = {0.f,0.f,0.f,0.f}, acc1 = {0.f,0.f,0.f,0.f};
    f32x4 acc2 = {0.f,0.f,0.f,0.f}, acc3 = {0.f,0.f,0.f,0.f};

    // 2-deep prefetch ring (static names)
    float4 a0, a1, a2, a3, b0, b1, b2, b3;
    {
        const float* hp = hgp + c0 * HC;
        a0 = *(const float4*)(hp);      a1 = *(const float4*)(hp + 16);
        a2 = *(const float4*)(hp + 32); a3 = *(const float4*)(hp + 48);
        const float* hq = hgp + (c0 + 1) * HC;
        b0 = *(const float4*)(hq);      b1 = *(const float4*)(hq + 16);
        b2 = *(const float4*)(hq + 32); b3 = *(const float4*)(hq + 48);
    }

    for (int c = 0; c < CPS; c += 2) {
        CHUNKW(c,     a0, a1, a2, a3);
        CHUNKW(c + 1, b0, b1, b2, b3);
    }

    // ---- cross-wave reduce: partials to LDS overlay ----
    __syncthreads();                  // all waves done with staging buffers
    float* red = (float*)smem;        // [8 waves][16 tok][68] = 34816 B
    {
        float* rw = red + w * 1088;
        #pragma unroll
        for (int r = 0; r < 4; ++r) {
            const int row = (4 * kq + r) * 68 + rx;
            rw[row +  0] = acc0[r];
            rw[row + 16] = acc1[r];
            rw[row + 32] = acc2[r];
            rw[row + 48] = acc3[r];
        }
    }
    __syncthreads();

    // ---- epilogue: 16 lanes per token, 32 tokens (512 threads) ----
    const int t   = tid >> 4;        // 0..31
    const int q   = tid & 15;
    const int tok = tok0 + t;
    const int gh  = t >> 4;          // token-half of this token
    const int tl  = t & 15;          // local token within half

    float lv[4];
    #pragma unroll
    for (int i = 0; i < 4; ++i) {
        const int o = tl * 68 + q + 16 * i;
        const float* rb = red + (size_t)(gh * 4) * 1088;
        lv[i] = (rb[o] + rb[1088 + o]) + (rb[2176 + o] + rb[3264 + o]);
    }

    float mx = lv[0];
    #pragma unroll
    for (int i = 1; i < 4; ++i) mx = fmaxf(mx, lv[i]);
    #pragma unroll
    for (int sh = 1; sh < 16; sh <<= 1) mx = fmaxf(mx, __shfl_xor(mx, sh, 64));

    float ex[4], psum = 0.0f;
    #pragma unroll
    for (int i = 0; i < 4; ++i) { ex[i] = expf(lv[i] - mx); psum += ex[i]; }
    #pragma unroll
    for (int sh = 1; sh < 16; sh <<= 1) psum += __shfl_xor(psum, sh, 64);
    const float inv = 1.0f / psum;

    float pr[4], selv[4];
    #pragma unroll
    for (int i = 0; i < 4; ++i) {
        pr[i]   = ex[i] * inv;
        selv[i] = pr[i] + bias[q + 16 * i];
    }

    float ws_[TOPC], wp[TOPC];
    int   wi[TOPC];
    #pragma unroll
    for (int k = 0; k < TOPC; ++k) {
        float bs = selv[0], bp = pr[0];
        int bi = q;
        #pragma unroll
        for (int i = 1; i < 4; ++i)
            if (selv[i] > bs) { bs = selv[i]; bp = pr[i]; bi = q + 16 * i; }
        #pragma unroll
        for (int sh = 1; sh < 16; sh <<= 1) {
            float os = __shfl_xor(bs, sh, 64);
            float op = __shfl_xor(bp, sh, 64);
            int   ob = __shfl_xor(bi, sh, 64);
            if (os > bs || (os == bs && ob < bi)) { bs = os; bp = op; bi = ob; }
        }
        ws_[k] = bs; wp[k] = bp; wi[k] = bi;
        #pragma unroll
        for (int i = 0; i < 4; ++i)
            if (q + 16 * i == bi) selv[i] = -INFINITY;
    }

    bool flag = false;
    #pragma unroll
    for (int k = 0; k < 8; ++k)
        flag = flag || (ws_[k] - ws_[k + 1] <
                        (ws_[k] + ws_[k + 1]) * MARGIN_REL + 1e-12f);

    {
        int   mywi = wi[0];
        float mywp = wp[0];
        #pragma unroll
        for (int k = 1; k < TOPC; ++k)
            if (q == k) { mywi = wi[k]; mywp = wp[k]; }
        if (flag && q < TOPC) {
            recI[(size_t)tok * 10 + q] = mywi;
            recF[(size_t)tok * 12 + q] = mywp;
        }
        if (flag && q == 0) {
            recF[(size_t)tok * 12 + 10] = mx;
            recF[(size_t)tok * 12 + 11] = inv;
            unsigned int o = atomicAdd(nflag, 1u);
            list[o] = (unsigned int)tok;
        }
    }

    int oi = wi[0];
    float opf = wp[0];
    #pragma unroll
    for (int k = 1; k < 8; ++k)
        if (q == k) { oi = wi[k]; opf = wp[k]; }

    float ps = 0.0f;
    #pragma unroll
    for (int k = 0; k < 8; ++k) ps += wp[k];
    const float rinv = 1.0f / (ps + 1e-9f);

    if (q < KK) {
        out[(size_t)tok * KK + q]           = opf * rinv;
        out[IDX_OFF + (size_t)tok * KK + q] = (float)oi;
    }

    unsigned long long mk = 0ull;
    #pragma unroll
    for (int k = 0; k < 8; ++k) mk |= (1ull << wi[k]);

    {
        float4 a;
        a.x = ((mk >> (4 * q + 0)) & 1ull) ? 1.0f : 0.0f;
        a.y = ((mk >> (4 * q + 1)) & 1ull) ? 1.0f : 0.0f;
        a.z = ((mk >> (4 * q + 2)) & 1ull) ? 1.0f : 0.0f;
        a.w = ((mk >> (4 * q + 3)) & 1ull) ? 1.0f : 0.0f;
        *(float4*)(out + MAP_OFF + (size_t)tok * EE + 4 * q) = a;
    }

    if (tile == 0 && tid == 0) out[AUX_OFF] = 0.0f;
}

// ---- fixup: one 256-thread block per flagged token (R17-validated) ----
__global__ __launch_bounds__(256, 4)
void fixup_kernel(const float* __restrict__ hidden,
                  const float* __restrict__ gate_w,
                  const float* __restrict__ bias,
                  const unsigned int* __restrict__ nflag,
                  const unsigned int* __restrict__ list,
                  const int* __restrict__ recI,
                  const float* __restrict__ recF,
                  float* __restrict__ out)
{
    __shared__ double redL[4][12];

    const int tid  = threadIdx.x;
    const int wv   = tid >> 6;
    const int lane = tid & 63;
    const unsigned int nf = *nflag;

    for (unsigned int i = blockIdx.x; i < nf; i += gridDim.x) {
        const int tok = (int)list[i];

        int   wk[TOPC];
        #pragma unroll
        for (int k = 0; k < TOPC; ++k) wk[k] = recI[(size_t)tok * 10 + k];
        const float mx  = recF[(size_t)tok * 12 + 10];
        const float inv = recF[(size_t)tok * 12 + 11];

        const float* hp = hidden + (size_t)tok * HH + tid * 8;
        float4 ha = *(const float4*)(hp);
        float4 hb = *(const float4*)(hp + 4);
        double h0 = ha.x, h1 = ha.y, h2 = ha.z, h3 = ha.w;
        double h4 = hb.x, h5 = hb.y, h6 = hb.z, h7 = hb.w;

        double l64[TOPC];
        #pragma unroll
        for (int k = 0; k < TOPC; ++k) {
            const float* wpt = gate_w + (size_t)wk[k] * HH + tid * 8;
            float4 wa = *(const float4*)(wpt);
            float4 wb = *(const float4*)(wpt + 4);
            double sacc = 0.0;
            sacc = fma(h0, (double)wa.x, sacc); sacc = fma(h1, (double)wa.y, sacc);
            sacc = fma(h2, (double)wa.z, sacc); sacc = fma(h3, (double)wa.w, sacc);
            sacc = fma(h4, (double)wb.x, sacc); sacc = fma(h5, (double)wb.y, sacc);
            sacc = fma(h6, (double)wb.z, sacc); sacc = fma(h7, (double)wb.w, sacc);
            l64[k] = sacc;
        }
        #pragma unroll
        for (int k = 0; k < TOPC; ++k)
            #pragma unroll
            for (int sh = 1; sh < 64; sh <<= 1)
                l64[k] += __shfl_xor(l64[k], sh, 64);
        if (lane == 0)
            #pragma unroll
            for (int k = 0; k < TOPC; ++k) redL[wv][k] = l64[k];
        __syncthreads();

        if (tid == 0) {
            double s64[TOPC];
            int    wi2[TOPC];
            float  wp2[TOPC];
            #pragma unroll
            for (int k = 0; k < TOPC; ++k) {
                double lk = redL[0][k] + redL[1][k] + redL[2][k] + redL[3][k];
                s64[k] = exp(lk - (double)mx) * (double)inv +
                         (double)bias[wk[k]];
                wi2[k] = wk[k];
                wp2[k] = recF[(size_t)tok * 12 + k];
            }
            #pragma unroll
            for (int a = 0; a < 8; ++a) {
                #pragma unroll
                for (int b = a + 1; b < TOPC; ++b) {
                    bool sw = (s64[b] > s64[a]) ||
                              (s64[b] == s64[a] && wi2[b] < wi2[a]);
                    if (sw) {
                        double td = s64[a]; s64[a] = s64[b]; s64[b] = td;
                        int    ti = wi2[a]; wi2[a] = wi2[b]; wi2[b] = ti;
                        float  tp = wp2[a]; wp2[a] = wp2[b]; wp2[b] = tp;
                    }
                }
            }
            float ps = 0.0f;
            #pragma unroll
            for (int k = 0; k < 8; ++k) ps += wp2[k];
            const float rinv = 1.0f / (ps + 1e-9f);
            unsigned long long mk = 0ull;
            #pragma unroll
            for (int k = 0; k < 8; ++k) {
                out[(size_t)tok * KK + k]           = wp2[k] * rinv;
                out[IDX_OFF + (size_t)tok * KK + k] = (float)wi2[k];
                mk |= (1ull << wi2[k]);
            }
            for (int e = 0; e < EE; ++e)
                out[MAP_OFF + (size_t)tok * EE + e] =
                    ((mk >> e) & 1ull) ? 1.0f : 0.0f;
        }
        __syncthreads();
    }
}

extern "C" void kernel_launch(void* const* d_in, const int* in_sizes, int n_in,
                              void* d_out, int out_size, void* d_ws, size_t ws_size,
                              hipStream_t stream) {
    const float* hidden = (const float*)d_in[0];
    const float* gate_w = (const float*)d_in[1];
    const float* bias   = (const float*)d_in[2];
    float* out = (float*)d_out;

    char* wsb = (char*)d_ws;
    unsigned short* wplanes = (unsigned short*)wsb;
    unsigned int* nflag = (unsigned int*)(wsb + NFLAG_B);
    unsigned int* list  = (unsigned int*)(wsb + LIST_B);
    int*          recI  = (int*)(wsb + RECI_B);
    float*        recF  = (float*)(wsb + RECF_B);

    prep_kernel<<<128, 256, 0, stream>>>(gate_w, wplanes, nflag);
    fused_gemm<<<NTILE, 512, 0, stream>>>(hidden, bias, wplanes, nflag, list,
                                          recI, recF, out);
    fixup_kernel<<<256, 256, 0, stream>>>(hidden, gate_w, bias, nflag, list,
                                          recI, recF, out);
}